// Round 16
// baseline (78.167 us; speedup 1.0000x reference)
//
#include <hip/hip_runtime.h>
#include <math.h>

#define B_ 8
#define N_ 1024
#define D_ 512
#define H_ 8
#define HD_ 64
#define DS_ 63
#define SCALE_ 0.125f
#define LOG2E_ 1.4426950408889634f
#define EPS_ 1e-7f
#define KT_ 64

typedef short bf16x8 __attribute__((ext_vector_type(8)));
typedef float f32x16 __attribute__((ext_vector_type(16)));

typedef const __attribute__((address_space(1))) unsigned int* gas_ptr;
typedef __attribute__((address_space(3))) unsigned int* las_ptr;

__device__ inline ushort f2bf(float f) {
    uint u = __float_as_uint(f);
    uint r = (u + 0x7FFFu + ((u >> 16) & 1u)) >> 16;
    return (ushort)r;
}

// ---------------- Kernel 0: fused x-cast + W-transpose prep ---------------
__global__ void prep_kernel(const float* __restrict__ x,
                            const float* __restrict__ Wq, const float* __restrict__ Wk,
                            const float* __restrict__ Wv,
                            ushort* __restrict__ xb, ushort* __restrict__ Wt) {
    __shared__ float til[64 * 65];
    const int bid = blockIdx.x;
    if (bid < 4096) {
        int i = bid * 256 + threadIdx.x;
        float4 v = ((const float4*)x)[i];
        ushort4 o;
        o.x = f2bf(v.x); o.y = f2bf(v.y); o.z = f2bf(v.z); o.w = f2bf(v.w);
        ((ushort4*)xb)[i] = o;
    } else {
        const int b2 = bid - 4096;            // 0..191
        const int g = b2 >> 3, kbase = (b2 & 7) * 64;
        const int mat = g >> 3, h = g & 7;
        const float* W = (mat == 0) ? Wq : (mat == 1) ? Wk : Wv;
        const float* src = W + (size_t)h * D_ * DS_ + (size_t)kbase * DS_;
        for (int i = threadIdx.x; i < 64 * DS_; i += 256) {
            int k = i / DS_, e = i - k * DS_;
            til[k * 65 + e] = src[i];
        }
        __syncthreads();
        for (int i = threadIdx.x; i < 64 * 64; i += 256) {
            int e = i >> 6, kk = i & 63;
            float v = (e < DS_) ? til[kk * 65 + e] : 0.f;
            Wt[((size_t)g * 64 + e) * D_ + kbase + kk] = f2bf(v);
        }
    }
}

// ---------------- Kernel 1: MFMA projection, 128x256 tile, 4 groups/block --
// grid (64 row-tiles, 6 group-quads), 256 thr = 4 waves (wr=row-half, wc=col-half).
// Wave owns 64x128: 2 A-frags + 4 B-frags = 6 reads -> 8 MFMAs (ratio 0.75,
// was 1.0). All 384 blocks co-resident at 2/CU. A L2-refetch halves (6 vs 12).
__global__ __launch_bounds__(256, 2)
void proj6_kernel(const ushort* __restrict__ Xb, const ushort* __restrict__ Wt,
                  const float* __restrict__ bq, const float* __restrict__ bk,
                  const float* __restrict__ bv,
                  ushort* __restrict__ Qo, ushort* __restrict__ Ko,
                  ushort* __restrict__ Vto)
{
    __shared__ char smem[49152];   // A[128][128B] @0, B[256][128B] @16K; epi reuse

    const int tid = threadIdx.x;
    const int wid = tid >> 6, lane = tid & 63;
    const int lm = lane & 31, g = lane >> 5;
    const int wr = wid & 1, wc = wid >> 1;
    const int R0 = blockIdx.x * 128;
    const int grp0 = blockIdx.y * 4;          // quad never spans mats (grp0%8 in {0,4})
    const int mat = grp0 >> 3;

    char* As = smem;
    char* Bs = smem + 16384;
    const ushort* Wg = Wt + (size_t)grp0 * 64 * D_;

    f32x16 acc[2][4];
#pragma unroll
    for (int a = 0; a < 2; a++)
#pragma unroll
        for (int n = 0; n < 4; n++) acc[a][n] = {0.f};

    const int asw = (lm & 7) << 4;

    for (int t = 0; t < 8; t++) {
        __syncthreads();                       // prior compute done
#pragma unroll
        for (int it = 0; it < 4; it++) {       // stage A (16KB: 128 rows)
            int ci = it * 256 + tid;
            int row = ci >> 3, cb = (ci & 7) * 16;
            const char* src = (const char*)(Xb + (size_t)(R0 + row) * D_ + t * KT_)
                              + (cb ^ ((row & 7) << 4));
            __builtin_amdgcn_global_load_lds((gas_ptr)src,
                (las_ptr)(As + it * 4096 + wid * 1024), 16, 0, 0);
        }
#pragma unroll
        for (int it = 0; it < 8; it++) {       // stage B (32KB: 256 rows = 4 groups)
            int ci = it * 256 + tid;
            int row = ci >> 3, cb = (ci & 7) * 16;
            const char* src = (const char*)(Wg + (size_t)row * D_ + t * KT_)
                              + (cb ^ ((row & 7) << 4));
            __builtin_amdgcn_global_load_lds((gas_ptr)src,
                (las_ptr)(Bs + it * 4096 + wid * 1024), 16, 0, 0);
        }
        __syncthreads();                       // vmcnt(0) drain + barrier
#pragma unroll
        for (int c = 0; c < 4; c++) {
            int kb = (c * 32 + g * 16) ^ asw;
            bf16x8 a0 = *(const bf16x8*)(As + (wr * 64 + lm) * 128 + kb);
            bf16x8 a1 = *(const bf16x8*)(As + (wr * 64 + 32 + lm) * 128 + kb);
            bf16x8 bfr[4];
#pragma unroll
            for (int n = 0; n < 4; n++)
                bfr[n] = *(const bf16x8*)(Bs + (wc * 128 + n * 32 + lm) * 128 + kb);
#pragma unroll
            for (int n = 0; n < 4; n++) {
                acc[0][n] = __builtin_amdgcn_mfma_f32_32x32x16_bf16(a0, bfr[n], acc[0][n], 0, 0, 0);
                acc[1][n] = __builtin_amdgcn_mfma_f32_32x32x16_bf16(a1, bfr[n], acc[1][n], 0, 0, 0);
            }
        }
    }
    __syncthreads();

    float* zs   = (float*)smem;                 // [128][65] = 33280B
    float* tval = (float*)(smem + 33280);       // [128]
    float* cval = tval + 128;                   // [128]
    const float* bptr = (mat == 0) ? bq : (mat == 1) ? bk : bv;
    const int b = R0 >> 10, n0 = R0 & (N_ - 1);

    for (int pass = 0; pass < 4; pass++) {      // one 64-col group per pass
        const int h = (grp0 + pass) & 7;
        if (pass) __syncthreads();              // prior out-writes done reading zs
        if (wc == (pass >> 1)) {
            // this wave holds the group's cols: n in {2*(pass&1), 2*(pass&1)+1}
            float bias[2];
#pragma unroll
            for (int ln = 0; ln < 2; ln++) {
                int e = ln * 32 + lm;
                bias[ln] = (e < DS_) ? bptr[h * DS_ + e] : 0.f;
            }
#pragma unroll
            for (int a = 0; a < 2; a++)
#pragma unroll
                for (int ln = 0; ln < 2; ln++) {
                    int n = (pass & 1) * 2 + ln;
#pragma unroll
                    for (int r = 0; r < 16; r++) {
                        int rm = (r & 3) + 8 * (r >> 2) + 4 * g;
                        float v = (ln == 0 ? acc[a][n][r] : acc[a][n][r]);
                        zs[(wr * 64 + a * 32 + rm) * 65 + ln * 32 + lm] = acc[a][n][r] + bias[ln];
                        (void)v;
                    }
                }
        }
        __syncthreads();
        if (tid < 128) {
            float ss = 0.f;
            for (int e = 0; e < DS_; e++) { float v = zs[tid * 65 + e]; ss += v * v; }
            float t = sqrtf(ss + 1.f);
            float w0, coef;
            if (mat == 0) {
                // fold SCALE and log2(e) into Q: softmax exp is native exp2
                w0 = -t * (SCALE_ * LOG2E_); coef = SCALE_ * LOG2E_;
            } else if (mat == 1) { w0 = t; coef = 1.f; }
            else {
                float tc = fmaxf(t, 1.f + EPS_);
                float d  = acoshf(tc);
                float dn = sqrtf(fmaxf(t * t - 1.f, EPS_));
                w0 = 0.f; coef = d / dn;
            }
            tval[tid] = w0; cval[tid] = coef;
        }
        __syncthreads();

        const int bh = b * H_ + h;
        if (mat == 2) {
            // V^T: row 0 = ONES (den-in-MFMA); keys PERMUTED within each
            // 32-block (swap bits 2<->3) for attn's contiguous b128 V-frag.
            for (int i = tid; i < 128 * 64; i += 256) {
                int e = i >> 7, nl = i & 127;
                float val = (e == 0) ? 1.0f : cval[nl] * zs[nl * 65 + e - 1];
                int np = (nl & ~12) | ((nl & 4) << 1) | ((nl & 8) >> 1);
                Vto[((size_t)bh * 64 + e) * N_ + n0 + np] = f2bf(val);
            }
        } else {
            ushort* dst = (mat == 0) ? Qo : Ko;
            for (int i = tid; i < 128 * 64; i += 256) {
                int rr = i >> 6, e = i & 63;
                float val = (e == 0) ? tval[rr] : cval[rr] * zs[rr * 65 + e - 1];
                dst[((size_t)bh * N_ + n0 + rr) * 64 + e] = f2bf(val);
            }
        }
    }
}

// ---------------- Kernel 2: MFMA attention (R15 green, unchanged) ----------
__global__ __launch_bounds__(512, 2)
void attn9_kernel(const ushort* __restrict__ Q, const ushort* __restrict__ K,
                  const ushort* __restrict__ Vt, float* __restrict__ out,
                  float* __restrict__ TS, float sconst)
{
    __shared__ char lds[32768];   // K[2][64][128B] @0, V[2][64][128B] @16K

    const int tid  = threadIdx.x;
    const int wid  = tid >> 6;                 // 0..7
    const int lane = tid & 63;
    const int lm = lane & 31, g = lane >> 5;

    const int bid = blockIdx.x;
    const int bh  = (bid >> 5) * 8 + (bid & 7);
    const int R0  = ((bid >> 3) & 3) * 256;
    const int qrow = R0 + wid * 32 + lm;

    bf16x8 qf[4];
    const ushort* qptr = Q + (((size_t)bh) * N_ + qrow) * 64 + g * 8;
#pragma unroll
    for (int c = 0; c < 4; c++)
        qf[c] = *(const bf16x8*)(qptr + c * 16);

    f32x16 acc0 = {0.f}, acc1 = {0.f};

    const ushort* kg = K  + ((size_t)bh) * N_ * 64;
    const ushort* vg = Vt + ((size_t)bh) * 64 * N_;

    auto stage = [&](int buf, int kt) {
        int row = tid >> 3, cb = (tid & 7) << 4;
        int sw = (row & 7) << 4;
        const char* srck = (const char*)(kg + (size_t)(kt + row) * 64) + (cb ^ sw);
        __builtin_amdgcn_global_load_lds((gas_ptr)srck,
            (las_ptr)(lds + buf * 8192 + wid * 1024), 16, 0, 0);
        const char* srcv = (const char*)(vg + (size_t)row * N_ + kt) + (cb ^ sw);
        __builtin_amdgcn_global_load_lds((gas_ptr)srcv,
            (las_ptr)(lds + 16384 + buf * 8192 + wid * 1024), 16, 0, 0);
    };

    stage(0, 0);
    for (int t = 0; t < 16; t++) {
        __syncthreads();                       // stage(t) drained, compute(t-1) done
        if (t < 15) stage((t + 1) & 1, (t + 1) * KT_);
        const int cur = t & 1;
        char* kbase = lds + cur * 8192;
        char* vbase = lds + 16384 + cur * 8192;

#pragma unroll
        for (int sub = 0; sub < 2; sub++) {
            // ---- S^T: 32 keys x 32 queries (base-2 scores) ----
            f32x16 st = {0.f};
            const int krow = sub * 32 + lm;
            const int ksw  = (krow & 7) << 4;
            __builtin_amdgcn_s_setprio(1);
#pragma unroll
            for (int c = 0; c < 4; c++) {
                bf16x8 kf = *(const bf16x8*)(kbase + krow * 128 + ((g * 16 + c * 32) ^ ksw));
                st = __builtin_amdgcn_mfma_f32_32x32x16_bf16(kf, qf[c], st, 0, 0, 0);
            }
            __builtin_amdgcn_s_setprio(0);
            // ---- p = 2^st (native v_exp_f32; st <= -0.18) ----
            float p[16];
#pragma unroll
            for (int rr = 0; rr < 16; rr++)
                p[rr] = __builtin_amdgcn_exp2f(st[rr]);
            union { uint u[8]; bf16x8 v[2]; } pu;
#pragma unroll
            for (int j = 0; j < 8; j++)
                pu.u[j] = __builtin_amdgcn_perm(__float_as_uint(p[2 * j + 1]),
                                                __float_as_uint(p[2 * j]), 0x07060302);
            // ---- PV: out^T += V^T * P^T (V keys pre-permuted: 1 b128/frag) --
            __builtin_amdgcn_s_setprio(1);
#pragma unroll
            for (int c = 0; c < 2; c++) {
#pragma unroll
                for (int dh = 0; dh < 2; dh++) {
                    const int vrow = dh * 32 + lm;
                    const int vsw  = (vrow & 7) << 4;
                    const int colb = sub * 64 + c * 32 + g * 16;
                    bf16x8 vf = *(const bf16x8*)(vbase + vrow * 128 + (colb ^ vsw));
                    if (dh == 0)
                        acc0 = __builtin_amdgcn_mfma_f32_32x32x16_bf16(vf, pu.v[c], acc0, 0, 0, 0);
                    else
                        acc1 = __builtin_amdgcn_mfma_f32_32x32x16_bf16(vf, pu.v[c], acc1, 0, 0, 0);
                }
            }
            __builtin_amdgcn_s_setprio(0);
        }
    }

    // ---- epilogue: den from acc0[0] (g==0), normalize, expmap0 ----
    float draw = acc0[0];
    float doth = __shfl_xor(draw, 32);
    float den  = (g == 0) ? draw : doth;
    if (g == 0) acc0[0] = 0.f;                 // exclude den slot from ss/out

    float invd = 1.f / den;
    float ss = 0.f;
#pragma unroll
    for (int j = 0; j < 16; j++) {
        acc0[j] *= invd; acc1[j] *= invd;
        ss += acc0[j] * acc0[j] + acc1[j] * acc1[j];
    }
    ss += __shfl_xor(ss, 32);
    float rr = sqrtf(fmaxf(ss, 1e-14f));
    float t  = coshf(rr);
    float coef = sconst * sinhf(rr) / rr;

    const int b = bh >> 3, h = bh & 7;
    const size_t ob = ((size_t)b * N_ + qrow) * 505 + (size_t)h * DS_;
#pragma unroll
    for (int j = 0; j < 16; j++) {
        int d = (j & 3) + 8 * (j >> 2) + 4 * g;
        if (d >= 1) out[ob + d] = coef * acc0[j];
        out[ob + d + 32] = coef * acc1[j];
    }
    if (g == 0) TS[((size_t)bh) * N_ + qrow] = t;
}

// ---------------- Kernel 3: cross-head t' --------------------------------
__global__ void tprime_kernel(const float* __restrict__ TS, float* __restrict__ out,
                              float sconst)
{
    int idx = blockIdx.x * 256 + threadIdx.x;
    if (idx >= B_ * N_) return;
    int b = idx >> 10, n = idx & (N_ - 1);
    float sum = 0.f;
#pragma unroll
    for (int h = 0; h < H_; h++) {
        float t = TS[((size_t)(b * H_ + h)) * N_ + n];
        sum += t * t - 1.f;
    }
    float tp = sqrtf(fmaxf(sconst * sconst * sum + 1.f, 1e-8f));
    out[(size_t)idx * 505] = tp;
}

static double digamma_(double x) {
    double r = 0.0;
    while (x < 20.0) { r -= 1.0 / x; x += 1.0; }
    double f = 1.0 / (x * x);
    return r + log(x) - 0.5 / x - f * (1.0 / 12.0 - f * (1.0 / 120.0 - f * (1.0 / 252.0)));
}

extern "C" void kernel_launch(void* const* d_in, const int* in_sizes, int n_in,
                              void* d_out, int out_size, void* d_ws, size_t ws_size,
                              hipStream_t stream) {
    const float* x  = (const float*)d_in[0];
    const float* Wq = (const float*)d_in[1];
    const float* bq = (const float*)d_in[2];
    const float* Wk = (const float*)d_in[3];
    const float* bk = (const float*)d_in[4];
    const float* Wv = (const float*)d_in[5];
    const float* bv = (const float*)d_in[6];
    float* out = (float*)d_out;

    const size_t QKV = (size_t)B_ * H_ * N_ * 64;
    ushort* Qd  = (ushort*)d_ws;
    ushort* Kd  = Qd + QKV;
    ushort* Vtd = Kd + QKV;
    ushort* Xb  = Vtd + QKV;
    ushort* Wtd = Xb + (size_t)B_ * N_ * D_;
    float*  TS  = (float*)(Wtd + (size_t)24 * 64 * D_);

    const float sconst = (float)exp(0.5 * (digamma_(H_ * DS_ / 2.0) - digamma_(DS_ / 2.0)));

    prep_kernel<<<4096 + 192, 256, 0, stream>>>(x, Wq, Wk, Wv, Xb, Wtd);
    proj6_kernel<<<dim3(64, 6), 256, 0, stream>>>(Xb, Wtd, bq, bk, bv, Qd, Kd, Vtd);
    attn9_kernel<<<256, 512, 0, stream>>>(Qd, Kd, Vtd, out, TS, sconst);
    tprime_kernel<<<(B_ * N_ + 255) / 256, 256, 0, stream>>>(TS, out, sconst);
}

// Round 17
// 67.337 us; speedup vs baseline: 1.1608x; 1.1608x over previous
//
#include <hip/hip_runtime.h>
#include <math.h>

#define B_ 8
#define N_ 1024
#define D_ 512
#define H_ 8
#define HD_ 64
#define DS_ 63
#define SCALE_ 0.125f
#define LOG2E_ 1.4426950408889634f
#define EPS_ 1e-7f
#define KT_ 64

typedef short bf16x8 __attribute__((ext_vector_type(8)));
typedef float f32x16 __attribute__((ext_vector_type(16)));

typedef const __attribute__((address_space(1))) unsigned int* gas_ptr;
typedef __attribute__((address_space(3))) unsigned int* las_ptr;

__device__ inline ushort f2bf(float f) {
    uint u = __float_as_uint(f);
    uint r = (u + 0x7FFFu + ((u >> 16) & 1u)) >> 16;
    return (ushort)r;
}

// ---------------- Kernel 0: fused x-cast + W-transpose prep ---------------
__global__ void prep_kernel(const float* __restrict__ x,
                            const float* __restrict__ Wq, const float* __restrict__ Wk,
                            const float* __restrict__ Wv,
                            ushort* __restrict__ xb, ushort* __restrict__ Wt) {
    __shared__ float til[64 * 65];
    const int bid = blockIdx.x;
    if (bid < 4096) {
        int i = bid * 256 + threadIdx.x;
        float4 v = ((const float4*)x)[i];
        ushort4 o;
        o.x = f2bf(v.x); o.y = f2bf(v.y); o.z = f2bf(v.z); o.w = f2bf(v.w);
        ((ushort4*)xb)[i] = o;
    } else {
        const int b2 = bid - 4096;            // 0..191
        const int g = b2 >> 3, kbase = (b2 & 7) * 64;
        const int mat = g >> 3, h = g & 7;
        const float* W = (mat == 0) ? Wq : (mat == 1) ? Wk : Wv;
        const float* src = W + (size_t)h * D_ * DS_ + (size_t)kbase * DS_;
        for (int i = threadIdx.x; i < 64 * DS_; i += 256) {
            int k = i / DS_, e = i - k * DS_;
            til[k * 65 + e] = src[i];
        }
        __syncthreads();
        for (int i = threadIdx.x; i < 64 * 64; i += 256) {
            int e = i >> 6, kk = i & 63;
            float v = (e < DS_) ? til[kk * 65 + e] : 0.f;
            Wt[((size_t)g * 64 + e) * D_ + kbase + kk] = f2bf(v);
        }
    }
}

// ---------------- Kernel 1: MFMA projection, single-buffered, 4 blocks/CU --
__global__ __launch_bounds__(256, 4)
void proj5_kernel(const ushort* __restrict__ Xb, const ushort* __restrict__ Wt,
                  const float* __restrict__ bq, const float* __restrict__ bk,
                  const float* __restrict__ bv,
                  ushort* __restrict__ Qo, ushort* __restrict__ Ko,
                  ushort* __restrict__ Vto)
{
    __shared__ char smem[34816];   // A[128][128B] @0, B[128][128B] @16K; epi reuse

    const int tid = threadIdx.x;
    const int wid = tid >> 6, lane = tid & 63;
    const int lm = lane & 31, g = lane >> 5;
    const int wr = wid & 1, wg = wid >> 1;
    const int R0 = blockIdx.x * 128;
    const int grp0 = blockIdx.y * 2;          // pair never spans mats
    const int mat = grp0 >> 3;

    char* As = smem;
    char* Bs = smem + 16384;
    const ushort* Wg = Wt + (size_t)grp0 * 64 * D_;

    f32x16 acc00 = {0.f}, acc01 = {0.f}, acc10 = {0.f}, acc11 = {0.f};
    const int asw = (lm & 7) << 4;

    for (int t = 0; t < 8; t++) {
        __syncthreads();                       // prior compute done
#pragma unroll
        for (int it = 0; it < 4; it++) {       // stage A (16KB)
            int ci = it * 256 + tid;
            int row = ci >> 3, cb = (ci & 7) * 16;
            const char* src = (const char*)(Xb + (size_t)(R0 + row) * D_ + t * KT_)
                              + (cb ^ ((row & 7) << 4));
            __builtin_amdgcn_global_load_lds((gas_ptr)src,
                (las_ptr)(As + it * 4096 + wid * 1024), 16, 0, 0);
        }
#pragma unroll
        for (int it = 0; it < 4; it++) {       // stage B (16KB)
            int ci = it * 256 + tid;
            int row = ci >> 3, cb = (ci & 7) * 16;
            const char* src = (const char*)(Wg + (size_t)row * D_ + t * KT_)
                              + (cb ^ ((row & 7) << 4));
            __builtin_amdgcn_global_load_lds((gas_ptr)src,
                (las_ptr)(Bs + it * 4096 + wid * 1024), 16, 0, 0);
        }
        __syncthreads();                       // vmcnt(0) drain + barrier
#pragma unroll
        for (int c = 0; c < 4; c++) {
            int kb = (c * 32 + g * 16) ^ asw;
            bf16x8 a0 = *(const bf16x8*)(As + (wr * 64 + lm) * 128 + kb);
            bf16x8 a1 = *(const bf16x8*)(As + (wr * 64 + 32 + lm) * 128 + kb);
            bf16x8 b0 = *(const bf16x8*)(Bs + (wg * 64 + lm) * 128 + kb);
            bf16x8 b1 = *(const bf16x8*)(Bs + (wg * 64 + 32 + lm) * 128 + kb);
            acc00 = __builtin_amdgcn_mfma_f32_32x32x16_bf16(a0, b0, acc00, 0, 0, 0);
            acc01 = __builtin_amdgcn_mfma_f32_32x32x16_bf16(a0, b1, acc01, 0, 0, 0);
            acc10 = __builtin_amdgcn_mfma_f32_32x32x16_bf16(a1, b0, acc10, 0, 0, 0);
            acc11 = __builtin_amdgcn_mfma_f32_32x32x16_bf16(a1, b1, acc11, 0, 0, 0);
        }
    }
    __syncthreads();

    float* zs   = (float*)smem;                 // [128][65] = 33280B
    float* tval = (float*)(smem + 33280);       // [128]
    float* cval = tval + 128;                   // [128]
    const float* bptr = (mat == 0) ? bq : (mat == 1) ? bk : bv;
    const int b = R0 >> 10, n0 = R0 & (N_ - 1);

    for (int pass = 0; pass < 2; pass++) {
        const int h = (grp0 + pass) & 7;
        if (pass) __syncthreads();
        if (wg == pass) {
            float ba = (lm < DS_) ? bptr[h * DS_ + lm] : 0.f;
            float bb = (lm + 32 < DS_) ? bptr[h * DS_ + lm + 32] : 0.f;
#pragma unroll
            for (int r = 0; r < 16; r++) {
                int rm = (r & 3) + 8 * (r >> 2) + 4 * g;
                zs[(wr * 64 + rm) * 65 + lm]           = acc00[r] + ba;
                zs[(wr * 64 + rm) * 65 + 32 + lm]      = acc01[r] + bb;
                zs[(wr * 64 + 32 + rm) * 65 + lm]      = acc10[r] + ba;
                zs[(wr * 64 + 32 + rm) * 65 + 32 + lm] = acc11[r] + bb;
            }
        }
        __syncthreads();
        if (tid < 128) {
            float ss = 0.f;
            for (int e = 0; e < DS_; e++) { float v = zs[tid * 65 + e]; ss += v * v; }
            float t = sqrtf(ss + 1.f);
            float w0, coef;
            if (mat == 0) {
                // fold SCALE and log2(e) into Q: softmax exp is native exp2
                w0 = -t * (SCALE_ * LOG2E_); coef = SCALE_ * LOG2E_;
            } else if (mat == 1) { w0 = t; coef = 1.f; }
            else {
                float tc = fmaxf(t, 1.f + EPS_);
                float d  = acoshf(tc);
                float dn = sqrtf(fmaxf(t * t - 1.f, EPS_));
                w0 = 0.f; coef = d / dn;
            }
            tval[tid] = w0; cval[tid] = coef;
        }
        __syncthreads();

        const int bh = b * H_ + h;
        if (mat == 2) {
            // V^T: row 0 = ONES (den-in-MFMA); keys PERMUTED within each
            // 32-block (swap bits 2<->3: involution) so attn's per-lane V
            // fragment is 16B-contiguous -> single ds_read_b128.
            for (int i = tid; i < 128 * 64; i += 256) {
                int e = i >> 7, nl = i & 127;
                float val = (e == 0) ? 1.0f : cval[nl] * zs[nl * 65 + e - 1];
                int np = (nl & ~12) | ((nl & 4) << 1) | ((nl & 8) >> 1);
                Vto[((size_t)bh * 64 + e) * N_ + n0 + np] = f2bf(val);
            }
        } else {
            ushort* dst = (mat == 0) ? Qo : Ko;
            for (int i = tid; i < 128 * 64; i += 256) {
                int rr = i >> 6, e = i & 63;
                float val = (e == 0) ? tval[rr] : cval[rr] * zs[rr * 65 + e - 1];
                dst[((size_t)bh * N_ + n0 + rr) * 64 + e] = f2bf(val);
            }
        }
    }
}

// ---------------- Kernel 2: MFMA attention, 8 waves share staged tile ------
// attn8 (R14 green) + key-permuted V: V fragment = ONE b128 read at
// colb = sub*64 + c*32 + g*16 (16B-aligned, swizzle-compatible).
__global__ __launch_bounds__(512, 2)
void attn9_kernel(const ushort* __restrict__ Q, const ushort* __restrict__ K,
                  const ushort* __restrict__ Vt, float* __restrict__ out,
                  float* __restrict__ TS, float sconst)
{
    __shared__ char lds[32768];   // K[2][64][128B] @0, V[2][64][128B] @16K

    const int tid  = threadIdx.x;
    const int wid  = tid >> 6;                 // 0..7
    const int lane = tid & 63;
    const int lm = lane & 31, g = lane >> 5;

    const int bid = blockIdx.x;
    const int bh  = (bid >> 5) * 8 + (bid & 7);
    const int R0  = ((bid >> 3) & 3) * 256;
    const int qrow = R0 + wid * 32 + lm;

    bf16x8 qf[4];
    const ushort* qptr = Q + (((size_t)bh) * N_ + qrow) * 64 + g * 8;
#pragma unroll
    for (int c = 0; c < 4; c++)
        qf[c] = *(const bf16x8*)(qptr + c * 16);

    f32x16 acc0 = {0.f}, acc1 = {0.f};

    const ushort* kg = K  + ((size_t)bh) * N_ * 64;
    const ushort* vg = Vt + ((size_t)bh) * 64 * N_;

    auto stage = [&](int buf, int kt) {
        int row = tid >> 3, cb = (tid & 7) << 4;
        int sw = (row & 7) << 4;
        const char* srck = (const char*)(kg + (size_t)(kt + row) * 64) + (cb ^ sw);
        __builtin_amdgcn_global_load_lds((gas_ptr)srck,
            (las_ptr)(lds + buf * 8192 + wid * 1024), 16, 0, 0);
        const char* srcv = (const char*)(vg + (size_t)row * N_ + kt) + (cb ^ sw);
        __builtin_amdgcn_global_load_lds((gas_ptr)srcv,
            (las_ptr)(lds + 16384 + buf * 8192 + wid * 1024), 16, 0, 0);
    };

    stage(0, 0);
    for (int t = 0; t < 16; t++) {
        __syncthreads();                       // stage(t) drained, compute(t-1) done
        if (t < 15) stage((t + 1) & 1, (t + 1) * KT_);
        const int cur = t & 1;
        char* kbase = lds + cur * 8192;
        char* vbase = lds + 16384 + cur * 8192;

#pragma unroll
        for (int sub = 0; sub < 2; sub++) {
            // ---- S^T: 32 keys x 32 queries (base-2 scores) ----
            f32x16 st = {0.f};
            const int krow = sub * 32 + lm;
            const int ksw  = (krow & 7) << 4;
            __builtin_amdgcn_s_setprio(1);
#pragma unroll
            for (int c = 0; c < 4; c++) {
                bf16x8 kf = *(const bf16x8*)(kbase + krow * 128 + ((g * 16 + c * 32) ^ ksw));
                st = __builtin_amdgcn_mfma_f32_32x32x16_bf16(kf, qf[c], st, 0, 0, 0);
            }
            __builtin_amdgcn_s_setprio(0);
            // ---- p = 2^st (native v_exp_f32; st <= -0.18) ----
            float p[16];
#pragma unroll
            for (int rr = 0; rr < 16; rr++)
                p[rr] = __builtin_amdgcn_exp2f(st[rr]);
            union { uint u[8]; bf16x8 v[2]; } pu;
#pragma unroll
            for (int j = 0; j < 8; j++)
                pu.u[j] = __builtin_amdgcn_perm(__float_as_uint(p[2 * j + 1]),
                                                __float_as_uint(p[2 * j]), 0x07060302);
            // ---- PV: out^T += V^T * P^T (V keys pre-permuted: 1 b128/frag) --
            __builtin_amdgcn_s_setprio(1);
#pragma unroll
            for (int c = 0; c < 2; c++) {
#pragma unroll
                for (int dh = 0; dh < 2; dh++) {
                    const int vrow = dh * 32 + lm;
                    const int vsw  = (vrow & 7) << 4;
                    const int colb = sub * 64 + c * 32 + g * 16;
                    bf16x8 vf = *(const bf16x8*)(vbase + vrow * 128 + (colb ^ vsw));
                    if (dh == 0)
                        acc0 = __builtin_amdgcn_mfma_f32_32x32x16_bf16(vf, pu.v[c], acc0, 0, 0, 0);
                    else
                        acc1 = __builtin_amdgcn_mfma_f32_32x32x16_bf16(vf, pu.v[c], acc1, 0, 0, 0);
                }
            }
            __builtin_amdgcn_s_setprio(0);
        }
    }

    // ---- epilogue: den from acc0[0] (g==0), normalize, expmap0 ----
    float draw = acc0[0];
    float doth = __shfl_xor(draw, 32);
    float den  = (g == 0) ? draw : doth;
    if (g == 0) acc0[0] = 0.f;                 // exclude den slot from ss/out

    float invd = 1.f / den;
    float ss = 0.f;
#pragma unroll
    for (int j = 0; j < 16; j++) {
        acc0[j] *= invd; acc1[j] *= invd;
        ss += acc0[j] * acc0[j] + acc1[j] * acc1[j];
    }
    ss += __shfl_xor(ss, 32);
    float rr = sqrtf(fmaxf(ss, 1e-14f));
    float t  = coshf(rr);
    float coef = sconst * sinhf(rr) / rr;

    const int b = bh >> 3, h = bh & 7;
    const size_t ob = ((size_t)b * N_ + qrow) * 505 + (size_t)h * DS_;
#pragma unroll
    for (int j = 0; j < 16; j++) {
        int d = (j & 3) + 8 * (j >> 2) + 4 * g;
        if (d >= 1) out[ob + d] = coef * acc0[j];
        out[ob + d + 32] = coef * acc1[j];
    }
    if (g == 0) TS[((size_t)bh) * N_ + qrow] = t;
}

// ---------------- Kernel 3: cross-head t' --------------------------------
__global__ void tprime_kernel(const float* __restrict__ TS, float* __restrict__ out,
                              float sconst)
{
    int idx = blockIdx.x * 256 + threadIdx.x;
    if (idx >= B_ * N_) return;
    int b = idx >> 10, n = idx & (N_ - 1);
    float sum = 0.f;
#pragma unroll
    for (int h = 0; h < H_; h++) {
        float t = TS[((size_t)(b * H_ + h)) * N_ + n];
        sum += t * t - 1.f;
    }
    float tp = sqrtf(fmaxf(sconst * sconst * sum + 1.f, 1e-8f));
    out[(size_t)idx * 505] = tp;
}

static double digamma_(double x) {
    double r = 0.0;
    while (x < 20.0) { r -= 1.0 / x; x += 1.0; }
    double f = 1.0 / (x * x);
    return r + log(x) - 0.5 / x - f * (1.0 / 12.0 - f * (1.0 / 120.0 - f * (1.0 / 252.0)));
}

extern "C" void kernel_launch(void* const* d_in, const int* in_sizes, int n_in,
                              void* d_out, int out_size, void* d_ws, size_t ws_size,
                              hipStream_t stream) {
    const float* x  = (const float*)d_in[0];
    const float* Wq = (const float*)d_in[1];
    const float* bq = (const float*)d_in[2];
    const float* Wk = (const float*)d_in[3];
    const float* bk = (const float*)d_in[4];
    const float* Wv = (const float*)d_in[5];
    const float* bv = (const float*)d_in[6];
    float* out = (float*)d_out;

    const size_t QKV = (size_t)B_ * H_ * N_ * 64;
    ushort* Qd  = (ushort*)d_ws;
    ushort* Kd  = Qd + QKV;
    ushort* Vtd = Kd + QKV;
    ushort* Xb  = Vtd + QKV;
    ushort* Wtd = Xb + (size_t)B_ * N_ * D_;
    float*  TS  = (float*)(Wtd + (size_t)24 * 64 * D_);

    const float sconst = (float)exp(0.5 * (digamma_(H_ * DS_ / 2.0) - digamma_(DS_ / 2.0)));

    prep_kernel<<<4096 + 192, 256, 0, stream>>>(x, Wq, Wk, Wv, Xb, Wtd);
    proj5_kernel<<<dim3(64, 12), 256, 0, stream>>>(Xb, Wtd, bq, bk, bv, Qd, Kd, Vtd);
    attn9_kernel<<<256, 512, 0, stream>>>(Qd, Kd, Vtd, out, TS, sconst);
    tprime_kernel<<<(B_ * N_ + 255) / 256, 256, 0, stream>>>(TS, out, sconst);
}